// Round 9
// baseline (336.239 us; speedup 1.0000x reference)
//
#include <hip/hip_runtime.h>
#include <hip/hip_bf16.h>

#define B_     8
#define CIN_   2
#define N_     512
#define C_     32
#define L_     64
#define LOUT_  61
#define BUF_   ((size_t)(8*32*512*64))   // 8,388,608 bf16 elements per scratch buffer

typedef __hip_bfloat16 bf16;
typedef unsigned short ushort_t;
typedef __attribute__((ext_vector_type(8))) unsigned short us8;
typedef __attribute__((ext_vector_type(8))) short bf16x8;
typedef __attribute__((ext_vector_type(4))) float f32x4;

static __device__ __forceinline__ float bits2f(ushort_t u) {
    return __uint_as_float(((unsigned)u) << 16);
}
static __device__ __forceinline__ ushort_t f2bits(float v) {   // RNE bf16 (finite inputs)
    unsigned u = __float_as_uint(v);
    return (ushort_t)((u + 0x7fffu + ((u >> 16) & 1u)) >> 16);
}

// ---------------- K0: start 1x1 conv (2->32 ch). One octet of l per thread.
__global__ void k_start(const float* __restrict__ x,
                        const float* __restrict__ Wst,
                        const float* __restrict__ bst,
                        ushort_t* __restrict__ h) {
    int idx = blockIdx.x * 256 + threadIdx.x;      // octet id, 1,048,576 total
    int l0 = (idx & 7) * 8;
    int n  = (idx >> 3) & 511;
    int o  = (idx >> 12) & 31;
    int b  = idx >> 17;
    float w0 = Wst[o * 2], w1 = Wst[o * 2 + 1], bb = bst[o];
    int xbase = (b * CIN_ * N_ + n) * L_ + l0;
    float va[8], vb[8];
    *(float4*)&va[0] = *(const float4*)(x + xbase);
    *(float4*)&va[4] = *(const float4*)(x + xbase + 4);
    *(float4*)&vb[0] = *(const float4*)(x + xbase + N_ * L_);
    *(float4*)&vb[4] = *(const float4*)(x + xbase + N_ * L_ + 4);
    us8 r;
    #pragma unroll
    for (int k = 0; k < 8; ++k) r[k] = f2bits(bb + va[k] * w0 + vb[k] * w1);
    *(us8*)(h + (size_t)idx * 8) = r;
}

// ---------------- K_T: adjT[m][n] = bf16(adj[n][m]), one-shot 512x512 transpose
__global__ void k_transA(const float* __restrict__ adj, ushort_t* __restrict__ adjT) {
    __shared__ float buf[64][65];
    int ti = blockIdx.x & 7;        // n-tile
    int tj = blockIdx.x >> 3;       // m-tile
    int t = threadIdx.x;
    for (int r = 0; r < 16; ++r) {
        int e = t + 256 * r;
        int rl = e >> 6, cl = e & 63;
        buf[rl][cl] = adj[(size_t)(ti * 64 + rl) * 512 + tj * 64 + cl];
    }
    __syncthreads();
    for (int r = 0; r < 16; ++r) {
        int e = t + 256 * r;
        int ml = e >> 6, nl = e & 63;
        adjT[(size_t)(tj * 64 + ml) * 512 + ti * 64 + nl] = f2bits(buf[nl][ml]);
    }
}

// ---------------- K_SQ: adj2T = adjT x adjT  (= (A^2)^T), bf16 MFMA, one-shot
__global__ __launch_bounds__(256, 2) void k_sq(const ushort_t* __restrict__ adjT,
                                               ushort_t* __restrict__ adj2T) {
    __shared__ __align__(16) ushort_t lds2[8192];   // As 4096 | Bs 4096; Ys aliases
    ushort_t* As = lds2;
    ushort_t* Bs = lds2 + 4096;
    int mt = blockIdx.x & 7, nc = blockIdx.x >> 3;
    int t = threadIdx.x, lane = t & 63, w = t >> 6;
    int la = lane & 15, q = lane >> 4;
    f32x4 acc[4];
    #pragma unroll
    for (int mi = 0; mi < 4; ++mi) acc[mi] = (f32x4)0.f;
    for (int p0 = 0; p0 < 512; p0 += 64) {
        __syncthreads();
        #pragma unroll
        for (int r = 0; r < 2; ++r) {
            int e = t + 256 * r, ml = e >> 3, oct = e & 7;
            int sw = ((oct + (ml >> 3)) & 7) << 3;
            *(us8*)(As + ml * 64 + sw) =
                *(const us8*)(adjT + (size_t)(mt * 64 + ml) * 512 + p0 + oct * 8);
            *(us8*)(Bs + ml * 64 + sw) =
                *(const us8*)(adjT + (size_t)(p0 + ml) * 512 + nc * 64 + oct * 8);
        }
        __syncthreads();
        #pragma unroll
        for (int ks = 0; ks < 2; ++ks) {
            bf16x8 a[4];
            #pragma unroll
            for (int mi = 0; mi < 4; ++mi) {
                int m = mi * 16 + la;
                int bl = (ks * 4 + q + (m >> 3)) & 7;
                a[mi] = *(const bf16x8*)(As + m * 64 + bl * 8);
            }
            bf16x8 bv;
            {
                int n = w * 16 + la;
                int rot = ((n >> 3) + ks * 4 + q) & 7;
                int col = rot * 8 + (n & 7);
                const ushort_t* p = Bs + (ks * 32 + q * 8) * 64 + col;
                #pragma unroll
                for (int j = 0; j < 8; ++j) bv[j] = (short)p[j * 64];
            }
            #pragma unroll
            for (int mi = 0; mi < 4; ++mi)
                acc[mi] = __builtin_amdgcn_mfma_f32_16x16x32_bf16(a[mi], bv, acc[mi], 0, 0, 0);
        }
    }
    __syncthreads();
    ushort_t* Ys = lds2;   // [64][72]
    #pragma unroll
    for (int mi = 0; mi < 4; ++mi)
        #pragma unroll
        for (int r = 0; r < 4; ++r)
            Ys[(mi * 16 + q * 4 + r) * 72 + w * 16 + la] = f2bits(acc[mi][r]);
    __syncthreads();
    #pragma unroll
    for (int r = 0; r < 2; ++r) {
        int e = t + 256 * r, ml = e >> 3, oct = e & 7;
        us8 v = *(const us8*)(Ys + ml * 72 + oct * 8);
        *(us8*)(adj2T + (size_t)(mt * 64 + ml) * 512 + nc * 64 + oct * 8) = v;
    }
}

// ---------------- K_TG: GT[b][c][l][n] = G[b][c][n][l], per-depth 64x64-tile transpose
__global__ void k_transG(const ushort_t* __restrict__ Gsrc, ushort_t* __restrict__ GT) {
    __shared__ __align__(16) ushort_t buf[64 * 72];   // [l][n]
    int b  = blockIdx.x >> 8;
    int c  = (blockIdx.x >> 3) & 31;
    int nt = blockIdx.x & 7;
    int t = threadIdx.x;
    size_t base = (size_t)(b * 32 + c) * 32768;
    int n0 = nt * 64;
    #pragma unroll
    for (int r = 0; r < 2; ++r) {        // n-fast lanes: conflict-free LDS writes
        int e = t + 256 * r;
        int n = e & 63, loct = e >> 6;
        us8 v = *(const us8*)(Gsrc + base + (size_t)(n0 + n) * 64 + loct * 8);
        #pragma unroll
        for (int k = 0; k < 8; ++k) buf[(loct * 8 + k) * 72 + n] = v[k];
    }
    __syncthreads();
    #pragma unroll
    for (int r = 0; r < 2; ++r) {
        int e = t + 256 * r;
        int oct = e & 7, l = (e >> 3) & 63;
        us8 v = *(const us8*)(buf + l * 72 + oct * 8);
        *(us8*)(GT + base + (size_t)l * 512 + n0 + oct * 8) = v;
    }
}

// ---------------- K1: FUSED MFMA gated conv + skip conv (+ optional output BN)
// H staged TRANSPOSED: Ht[node][l][c] (stride 40 us) so conv B-frags are b128.
__global__ __launch_bounds__(256, 2) void k_gs_mfma(
        const ushort_t* __restrict__ h,
        const float* __restrict__ Wf, const float* __restrict__ bfp,
        const float* __restrict__ Wg, const float* __restrict__ bgp,
        const float* __restrict__ Wsk, const float* __restrict__ bsk,
        ushort_t* __restrict__ G, float* __restrict__ out,
        int Llen, int off, int mode, int storeG,
        const float* __restrict__ og, const float* __restrict__ obb) {
    __shared__ __align__(16) ushort_t Ht[4 * 66 * 40];  // [node][l 0..65][c], 21120 us
    __shared__ __align__(16) ushort_t Hs[128 * 72];     // G-tile -> St(float[128][36])
    __shared__ __align__(16) ushort_t Asf[32 * 72];
    __shared__ __align__(16) ushort_t Asg[32 * 72];
    __shared__ __align__(16) ushort_t As2[32 * 40];
    __shared__ float bfv[32], bgv[32], bsv[32];
    int t = threadIdx.x;
    int b = blockIdx.x >> 7, n0 = (blockIdx.x & 127) * 4;
    int lane = t & 63, w = t >> 6;
    int la = lane & 15, q = lane >> 4;

    // weights -> LDS (bf16 rows [o][k])
    {
        int o = t >> 3, k8 = (t & 7) * 8;
        us8 vf, vg;
        #pragma unroll
        for (int i = 0; i < 8; ++i) {
            int k = k8 + i, c = k & 31, tap = k >> 5;
            vf[i] = f2bits(Wf[o * 64 + c * 2 + tap]);
            vg[i] = f2bits(Wg[o * 64 + c * 2 + tap]);
        }
        *(us8*)(Asf + o * 72 + k8) = vf;
        *(us8*)(Asg + o * 72 + k8) = vg;
        if (k8 < 32) {
            us8 vs;
            #pragma unroll
            for (int i = 0; i < 8; ++i) vs[i] = f2bits(Wsk[o * 32 + k8 + i]);
            *(us8*)(As2 + o * 40 + k8) = vs;
        }
        if (t < 32) { bfv[t] = bfp[t]; bgv[t] = bgp[t]; bsv[t] = bsk[t]; }
    }
    // zero Ht rows [Llen, 66) (disjoint from staged rows)
    #pragma unroll
    for (int r = 0; r < 2; ++r) {
        int idx = t + 256 * r;
        int lz = Llen + (idx >> 7);
        int node = (idx >> 5) & 3, c = idx & 31;
        if (lz < 66) Ht[(node * 66 + lz) * 40 + c] = 0;
    }
    // stage H transposed: read rows (c,node) l-contig, scatter to Ht[node][l][c]
    const ushort_t* hb = h + (size_t)(b * 32) * 512 * 64;
    #pragma unroll
    for (int r = 0; r < 4; ++r) {
        int e = t + 256 * r;
        int row = e & 127, loct = e >> 7;
        int c = row >> 2, node = row & 3;
        us8 v = *(const us8*)(hb + ((size_t)c * 512 + n0 + node) * 64 + loct * 8);
        #pragma unroll
        for (int k = 0; k < 8; ++k) {
            int l = loct * 8 + k;
            if (l < Llen) Ht[(node * 66 + l) * 40 + c] = v[k];
        }
    }
    __syncthreads();

    bf16x8 af[2][2], ag[2][2];
    #pragma unroll
    for (int mt = 0; mt < 2; ++mt)
        #pragma unroll
        for (int ks = 0; ks < 2; ++ks) {
            af[mt][ks] = *(const bf16x8*)(Asf + (mt * 16 + la) * 72 + ks * 32 + q * 8);
            ag[mt][ks] = *(const bf16x8*)(Asg + (mt * 16 + la) * 72 + ks * 32 + q * 8);
        }

    // conv MFMA: B-frags now b128 from Ht (tap = ks reads row l+ks)
    f32x4 fa[2][4], ga[2][4];
    #pragma unroll
    for (int mt = 0; mt < 2; ++mt)
        #pragma unroll
        for (int ct = 0; ct < 4; ++ct) { fa[mt][ct] = (f32x4)0.f; ga[mt][ct] = (f32x4)0.f; }
    #pragma unroll
    for (int ct = 0; ct < 4; ++ct) {
        int lcol = ct * 16 + la;
        #pragma unroll
        for (int ks = 0; ks < 2; ++ks) {
            bf16x8 bv = *(const bf16x8*)(Ht + (w * 66 + lcol + ks) * 40 + q * 8);
            #pragma unroll
            for (int mt = 0; mt < 2; ++mt) {
                fa[mt][ct] = __builtin_amdgcn_mfma_f32_16x16x32_bf16(af[mt][ks], bv, fa[mt][ct], 0, 0, 0);
                ga[mt][ct] = __builtin_amdgcn_mfma_f32_16x16x32_bf16(ag[mt][ks], bv, ga[mt][ct], 0, 0, 0);
            }
        }
    }

    // activation -> G tile in Hs (rows o*4+node, disjoint per wave)
    #pragma unroll
    for (int mt = 0; mt < 2; ++mt)
        #pragma unroll
        for (int ct = 0; ct < 4; ++ct)
            #pragma unroll
            for (int r = 0; r < 4; ++r) {
                int o = mt * 16 + q * 4 + r;
                float fv = fa[mt][ct][r] + bfv[o];
                float gv = ga[mt][ct][r] + bgv[o];
                float ef = __expf(2.f * fv);
                float act = (1.f - 2.f / (ef + 1.f)) * (1.f / (1.f + __expf(-gv)));
                int l = ct * 16 + la;
                int row = o * 4 + w;
                int sw = ((l >> 3) + row + (row >> 5)) & 7;
                Hs[row * 72 + sw * 8 + (l & 7)] = f2bits(act);
            }

    // skip MFMA (own wave's rows)
    bf16x8 a2[2];
    a2[0] = *(const bf16x8*)(As2 + la * 40 + q * 8);
    a2[1] = *(const bf16x8*)(As2 + (16 + la) * 40 + q * 8);
    f32x4 sa[2][4];
    #pragma unroll
    for (int mt = 0; mt < 2; ++mt)
        #pragma unroll
        for (int ct = 0; ct < 4; ++ct) sa[mt][ct] = (f32x4)0.f;
    #pragma unroll
    for (int ct = 0; ct < 4; ++ct) {
        int le = ct * 16 + la + off;
        bf16x8 bv;
        #pragma unroll
        for (int j = 0; j < 8; ++j) {
            int row = 32 * q + 4 * j + w;
            int pos = (le < 64) ? ((((le >> 3) + row + q) & 7) * 8 + (le & 7)) : le;
            bv[j] = (short)Hs[row * 72 + pos];
        }
        sa[0][ct] = __builtin_amdgcn_mfma_f32_16x16x32_bf16(a2[0], bv, sa[0][ct], 0, 0, 0);
        sa[1][ct] = __builtin_amdgcn_mfma_f32_16x16x32_bf16(a2[1], bv, sa[1][ct], 0, 0, 0);
    }
    __syncthreads();

    if (storeG) {
        #pragma unroll
        for (int r = 0; r < 4; ++r) {
            int e = t + 256 * r;
            int row = e >> 3, oct = e & 7;
            int sw = (oct + row + (row >> 5)) & 7;
            us8 v = *(const us8*)(Hs + row * 72 + sw * 8);
            *(us8*)(G + ((size_t)(b * 32 + (row >> 2)) * 512 + n0 + (row & 3)) * 64 + oct * 8) = v;
        }
    }
    __syncthreads();

    float* St = (float*)Hs;
    const float rbn = rsqrtf(1.f + 1e-5f);
    #pragma unroll
    for (int half = 0; half < 2; ++half) {
        if ((w >> 1) == half) {
            #pragma unroll
            for (int mt = 0; mt < 2; ++mt)
                #pragma unroll
                for (int ct = 0; ct < 4; ++ct) {
                    int col = (w & 1) * 64 + ct * 16 + la;
                    int ob = mt * 16 + q * 4;
                    float4 sv = make_float4(sa[mt][ct][0] + bsv[ob],
                                            sa[mt][ct][1] + bsv[ob + 1],
                                            sa[mt][ct][2] + bsv[ob + 2],
                                            sa[mt][ct][3] + bsv[ob + 3]);
                    *(float4*)(St + col * 36 + ob) = sv;
                }
        }
        __syncthreads();
        {
            int col = t >> 1, o0 = (t & 1) * 16;
            int nr = half * 2 + (col >> 6), l = col & 63;
            if (l < LOUT_) {
                float* po = out + ((size_t)(b * LOUT_ + l) * 512 + n0 + nr) * 32 + o0;
                #pragma unroll
                for (int i = 0; i < 4; ++i) {
                    float4 s = *(float4*)(St + col * 36 + o0 + i * 4);
                    if (mode == 0) {
                        *(float4*)(po + i * 4) = s;
                    } else {
                        float4 old = *(float4*)(po + i * 4);
                        float4 vv = make_float4(old.x + s.x, old.y + s.y,
                                                old.z + s.z, old.w + s.w);
                        if (mode == 2) {
                            int ob = o0 + i * 4;
                            vv.x = vv.x * (og[ob] * rbn) + obb[ob];
                            vv.y = vv.y * (og[ob + 1] * rbn) + obb[ob + 1];
                            vv.z = vv.z * (og[ob + 2] * rbn) + obb[ob + 2];
                            vv.w = vv.w * (og[ob + 3] * rbn) + obb[ob + 3];
                        }
                        *(float4*)(po + i * 4) = vv;
                    }
                }
            }
        }
        __syncthreads();
    }
}

// ---------------- K3a: dual MFMA diffusion from GT (all-b128 fragments)
__global__ __launch_bounds__(256, 2) void k_diffuse2_gt(
        const ushort_t* __restrict__ GT, const ushort_t* __restrict__ adjT,
        const ushort_t* __restrict__ adj2T,
        ushort_t* __restrict__ Y1, ushort_t* __restrict__ Y2) {
    __shared__ __align__(16) ushort_t lds[16384];  // As1|As2|Xs_t; Ys aliases
    ushort_t* As1 = lds;
    ushort_t* As2 = lds + 4096;
    ushort_t* Xs  = lds + 8192;                    // [2 c][64 l][64 n] swizzled
    int cp = blockIdx.x & 15;
    int mt = (blockIdx.x >> 4) & 7;
    int b  = blockIdx.x >> 7;
    int t  = threadIdx.x;
    int lane = t & 63, w = t >> 6;
    int c_loc = w & 1, lh = w >> 1;
    int m0 = mt * 64;
    int la = lane & 15, q = lane >> 4;
    const ushort_t* GTb = GT + (size_t)(b * 32 + cp * 2) * 32768;
    f32x4 acc1[4][2], acc2[4][2];
    #pragma unroll
    for (int mi = 0; mi < 4; ++mi)
        #pragma unroll
        for (int li = 0; li < 2; ++li) { acc1[mi][li] = (f32x4)0.f; acc2[mi][li] = (f32x4)0.f; }

    for (int n0 = 0; n0 < 512; n0 += 64) {
        __syncthreads();
        #pragma unroll
        for (int r = 0; r < 2; ++r) {
            int e = t + 256 * r;
            int ml = e >> 3, oct = e & 7;
            int sw = ((oct + (ml >> 3)) & 7) << 3;
            *(us8*)(As1 + ml * 64 + sw) =
                *(const us8*)(adjT + (size_t)(m0 + ml) * 512 + n0 + oct * 8);
            *(us8*)(As2 + ml * 64 + sw) =
                *(const us8*)(adj2T + (size_t)(m0 + ml) * 512 + n0 + oct * 8);
        }
        #pragma unroll
        for (int r = 0; r < 4; ++r) {              // stage Xs_t rows (c,l), n-contig
            int e = t + 256 * r;
            int row = e >> 3, oct = e & 7;         // row = cl*64 + l
            int cl = row >> 6, l = row & 63;
            us8 v = *(const us8*)(GTb + (size_t)cl * 32768 + (size_t)l * 512 + n0 + oct * 8);
            *(us8*)(Xs + cl * 4096 + l * 64 + (((oct + (l >> 3)) & 7) << 3)) = v;
        }
        __syncthreads();
        #pragma unroll
        for (int ks = 0; ks < 2; ++ks) {
            bf16x8 a1[4], a2v[4];
            #pragma unroll
            for (int mi = 0; mi < 4; ++mi) {
                int m = mi * 16 + la;
                int bl = (ks * 4 + q + (m >> 3)) & 7;
                a1[mi]  = *(const bf16x8*)(As1 + m * 64 + bl * 8);
                a2v[mi] = *(const bf16x8*)(As2 + m * 64 + bl * 8);
            }
            bf16x8 bb[2];
            #pragma unroll
            for (int li = 0; li < 2; ++li) {       // b128: row l, n-contig
                int l = lh * 32 + li * 16 + la;
                int bl = (ks * 4 + q + (l >> 3)) & 7;
                bb[li] = *(const bf16x8*)(Xs + c_loc * 4096 + l * 64 + bl * 8);
            }
            #pragma unroll
            for (int mi = 0; mi < 4; ++mi)
                #pragma unroll
                for (int li = 0; li < 2; ++li) {
                    acc1[mi][li] = __builtin_amdgcn_mfma_f32_16x16x32_bf16(a1[mi], bb[li], acc1[mi][li], 0, 0, 0);
                    acc2[mi][li] = __builtin_amdgcn_mfma_f32_16x16x32_bf16(a2v[mi], bb[li], acc2[mi][li], 0, 0, 0);
                }
        }
    }
    ushort_t* Ys = lds;                            // [2][64][72]
    #pragma unroll
    for (int pass = 0; pass < 2; ++pass) {
        __syncthreads();
        f32x4 (*src)[2] = pass ? acc2 : acc1;
        #pragma unroll
        for (int mi = 0; mi < 4; ++mi)
            #pragma unroll
            for (int li = 0; li < 2; ++li)
                #pragma unroll
                for (int r = 0; r < 4; ++r) {
                    int row = mi * 16 + q * 4 + r;
                    int col = lh * 32 + li * 16 + la;
                    Ys[c_loc * 4608 + row * 72 + col] = f2bits(src[mi][li][r]);
                }
        __syncthreads();
        ushort_t* Yo = pass ? Y2 : Y1;
        int c = t >> 7, mrem = t & 127;
        int m = mrem >> 1, lq = mrem & 1;
        #pragma unroll
        for (int r = 0; r < 4; ++r) {
            int l0 = lq * 32 + r * 8;
            us8 v = *(const us8*)(Ys + c * 4608 + m * 72 + l0);
            *(us8*)(Yo + ((size_t)(b * 32 + cp * 2 + c) * 512 + m0 + m) * 64 + l0) = v;
        }
    }
}

// ---------------- K3b: fallback dual diffusion from CNL X (scalar B-gather)
__global__ __launch_bounds__(256, 2) void k_diffuse2_cnl(
        const ushort_t* __restrict__ X, const ushort_t* __restrict__ adjT,
        const ushort_t* __restrict__ adj2T,
        ushort_t* __restrict__ Y1, ushort_t* __restrict__ Y2) {
    __shared__ __align__(16) ushort_t lds[16384];
    ushort_t* As1 = lds;
    ushort_t* As2 = lds + 4096;
    ushort_t* Xs  = lds + 8192;
    int cp = blockIdx.x & 15;
    int mt = (blockIdx.x >> 4) & 7;
    int b  = blockIdx.x >> 7;
    int t  = threadIdx.x;
    int lane = t & 63, w = t >> 6;
    int c_loc = w & 1, lh = w >> 1;
    int m0 = mt * 64;
    int la = lane & 15, q = lane >> 4;
    const ushort_t* Xb = X + (size_t)(b * 32 + cp * 2) * 512 * 64;
    f32x4 acc1[4][2], acc2[4][2];
    #pragma unroll
    for (int mi = 0; mi < 4; ++mi)
        #pragma unroll
        for (int li = 0; li < 2; ++li) { acc1[mi][li] = (f32x4)0.f; acc2[mi][li] = (f32x4)0.f; }
    for (int n0 = 0; n0 < 512; n0 += 64) {
        __syncthreads();
        #pragma unroll
        for (int r = 0; r < 2; ++r) {
            int e = t + 256 * r;
            int ml = e >> 3, oct = e & 7;
            int sw = ((oct + (ml >> 3)) & 7) << 3;
            *(us8*)(As1 + ml * 64 + sw) =
                *(const us8*)(adjT + (size_t)(m0 + ml) * 512 + n0 + oct * 8);
            *(us8*)(As2 + ml * 64 + sw) =
                *(const us8*)(adj2T + (size_t)(m0 + ml) * 512 + n0 + oct * 8);
        }
        #pragma unroll
        for (int r = 0; r < 4; ++r) {
            int e = t + 256 * r;
            int cl = e >> 9, nl = (e >> 3) & 63, oct = e & 7;
            us8 v = *(const us8*)(Xb + ((size_t)cl * 512 + n0 + nl) * 64 + oct * 8);
            *(us8*)(Xs + cl * 4096 + nl * 64 + (((oct + (nl >> 3)) & 7) << 3)) = v;
        }
        __syncthreads();
        #pragma unroll
        for (int ks = 0; ks < 2; ++ks) {
            bf16x8 a1[4], a2v[4];
            #pragma unroll
            for (int mi = 0; mi < 4; ++mi) {
                int m = mi * 16 + la;
                int bl = (ks * 4 + q + (m >> 3)) & 7;
                a1[mi]  = *(const bf16x8*)(As1 + m * 64 + bl * 8);
                a2v[mi] = *(const bf16x8*)(As2 + m * 64 + bl * 8);
            }
            bf16x8 bb[2];
            #pragma unroll
            for (int li = 0; li < 2; ++li) {
                int l = lh * 32 + li * 16 + la;
                int rot = ((l >> 3) + ks * 4 + q) & 7;
                int col = rot * 8 + (l & 7);
                const ushort_t* p = Xs + c_loc * 4096 + (ks * 32 + q * 8) * 64 + col;
                bf16x8 v;
                #pragma unroll
                for (int j = 0; j < 8; ++j) v[j] = (short)p[j * 64];
                bb[li] = v;
            }
            #pragma unroll
            for (int mi = 0; mi < 4; ++mi)
                #pragma unroll
                for (int li = 0; li < 2; ++li) {
                    acc1[mi][li] = __builtin_amdgcn_mfma_f32_16x16x32_bf16(a1[mi], bb[li], acc1[mi][li], 0, 0, 0);
                    acc2[mi][li] = __builtin_amdgcn_mfma_f32_16x16x32_bf16(a2v[mi], bb[li], acc2[mi][li], 0, 0, 0);
                }
        }
    }
    ushort_t* Ys = lds;
    #pragma unroll
    for (int pass = 0; pass < 2; ++pass) {
        __syncthreads();
        f32x4 (*src)[2] = pass ? acc2 : acc1;
        #pragma unroll
        for (int mi = 0; mi < 4; ++mi)
            #pragma unroll
            for (int li = 0; li < 2; ++li)
                #pragma unroll
                for (int r = 0; r < 4; ++r) {
                    int row = mi * 16 + q * 4 + r;
                    int col = lh * 32 + li * 16 + la;
                    Ys[c_loc * 4608 + row * 72 + col] = f2bits(src[mi][li][r]);
                }
        __syncthreads();
        ushort_t* Yo = pass ? Y2 : Y1;
        int c = t >> 7, mrem = t & 127;
        int m = mrem >> 1, lq = mrem & 1;
        #pragma unroll
        for (int r = 0; r < 4; ++r) {
            int l0 = lq * 32 + r * 8;
            us8 v = *(const us8*)(Ys + c * 4608 + m * 72 + l0);
            *(us8*)(Yo + ((size_t)(b * 32 + cp * 2 + c) * 512 + m0 + m) * 64 + l0) = v;
        }
    }
}

// ---------------- K4: MFMA graph-conv(96->32) + gcBN + residual + BN, in place over G.
__global__ __launch_bounds__(256, 2) void k_gc3_mfma(
        ushort_t* __restrict__ G, const ushort_t* __restrict__ X1,
        const ushort_t* __restrict__ X2, const ushort_t* __restrict__ hres,
        const float* __restrict__ Wgc, const float* __restrict__ bgc,
        const float* __restrict__ gg, const float* __restrict__ gb,
        const float* __restrict__ bg2, const float* __restrict__ bb2) {
    __shared__ __align__(16) ushort_t cat[384 * 72];   // B rows k*4+nr; reused as out tile
    __shared__ __align__(16) ushort_t hr[128 * 64];
    __shared__ __align__(16) ushort_t Aw[32 * 104];
    __shared__ float prm[5][32];
    int t = threadIdx.x;
    int b = blockIdx.x >> 7, n0 = (blockIdx.x & 127) * 4;
    int lane = t & 63, w = t >> 6;
    int la = lane & 15, q = lane >> 4;

    #pragma unroll
    for (int r = 0; r < 12; ++r) {
        int e = t + 256 * r;
        int row = e >> 3, oct = e & 7;
        int k = row >> 2;
        const ushort_t* src = (k < 32) ? G : ((k < 64) ? X1 : X2);
        us8 v = *(const us8*)(src + ((size_t)(b * 32 + (k & 31)) * 512 + n0 + (row & 3)) * 64 + oct * 8);
        int sw = (oct + row + (row >> 5)) & 7;
        *(us8*)(cat + row * 72 + sw * 8) = v;
    }
    #pragma unroll
    for (int r = 0; r < 4; ++r) {
        int e = t + 256 * r;
        int row = e >> 3, oct = e & 7;
        us8 v = *(const us8*)(hres + ((size_t)(b * 32 + (row >> 2)) * 512 + n0 + (row & 3)) * 64 + oct * 8);
        *(us8*)(hr + row * 64 + oct * 8) = v;
    }
    for (int e = t; e < 384; e += 256) {
        int o = e / 12, oct = e % 12;
        us8 v;
        #pragma unroll
        for (int i = 0; i < 8; ++i) v[i] = f2bits(Wgc[o * 96 + oct * 8 + i]);
        *(us8*)(Aw + o * 104 + oct * 8) = v;
    }
    if (t < 32) {
        prm[0][t] = bgc[t]; prm[1][t] = gg[t]; prm[2][t] = gb[t];
        prm[3][t] = bg2[t]; prm[4][t] = bb2[t];
    }
    __syncthreads();

    bf16x8 a[2][3];
    #pragma unroll
    for (int mt = 0; mt < 2; ++mt)
        #pragma unroll
        for (int ks = 0; ks < 3; ++ks)
            a[mt][ks] = *(const bf16x8*)(Aw + (mt * 16 + la) * 104 + ks * 32 + q * 8);

    f32x4 acc[2][4];
    #pragma unroll
    for (int mt = 0; mt < 2; ++mt)
        #pragma unroll
        for (int ct = 0; ct < 4; ++ct) acc[mt][ct] = (f32x4)0.f;
    #pragma unroll
    for (int ct = 0; ct < 4; ++ct) {
        int le = ct * 16 + la;
        #pragma unroll
        for (int ks = 0; ks < 3; ++ks) {
            bf16x8 bv;
            #pragma unroll
            for (int j = 0; j < 8; ++j) {
                int row = (ks * 32 + q * 8 + j) * 4 + w;
                int sw = ((le >> 3) + row + (row >> 5)) & 7;
                bv[j] = (short)cat[row * 72 + sw * 8 + (le & 7)];
            }
            acc[0][ct] = __builtin_amdgcn_mfma_f32_16x16x32_bf16(a[0][ks], bv, acc[0][ct], 0, 0, 0);
            acc[1][ct] = __builtin_amdgcn_mfma_f32_16x16x32_bf16(a[1][ks], bv, acc[1][ct], 0, 0, 0);
        }
    }
    __syncthreads();

    const float rbn = rsqrtf(1.f + 1e-5f);
    #pragma unroll
    for (int mt = 0; mt < 2; ++mt)
        #pragma unroll
        for (int ct = 0; ct < 4; ++ct)
            #pragma unroll
            for (int r = 0; r < 4; ++r) {
                int o = mt * 16 + q * 4 + r;
                int l = ct * 16 + la;
                float v = acc[mt][ct][r] + prm[0][o];
                v = v * (prm[1][o] * rbn) + prm[2][o];
                float res = (l < 63) ? bits2f(hr[(o * 4 + w) * 64 + l + 1]) : 0.f;
                v = (v + res) * (prm[3][o] * rbn) + prm[4][o];
                int row = o * 4 + w;
                int sw = ((l >> 3) + row + (row >> 5)) & 7;
                cat[row * 72 + sw * 8 + (l & 7)] = f2bits(v);
            }
    __syncthreads();
    #pragma unroll
    for (int r = 0; r < 4; ++r) {
        int e = t + 256 * r;
        int row = e >> 3, oct = e & 7;
        int sw = (oct + row + (row >> 5)) & 7;
        us8 v = *(const us8*)(cat + row * 72 + sw * 8);
        *(us8*)(G + ((size_t)(b * 32 + (row >> 2)) * 512 + n0 + (row & 3)) * 64 + oct * 8) = v;
    }
}

extern "C" void kernel_launch(void* const* d_in, const int* in_sizes, int n_in,
                              void* d_out, int out_size, void* d_ws, size_t ws_size,
                              hipStream_t stream) {
    const float* x      = (const float*)d_in[0];
    const float* adj    = (const float*)d_in[1];
    const float* Wstart = (const float*)d_in[2];
    const float* bstart = (const float*)d_in[3];
    const float* Wf     = (const float*)d_in[4];
    const float* bf_    = (const float*)d_in[5];
    const float* Wg     = (const float*)d_in[6];
    const float* bg     = (const float*)d_in[7];
    const float* Wskip  = (const float*)d_in[8];
    const float* bskip  = (const float*)d_in[9];
    const float* Wgc    = (const float*)d_in[10];
    const float* bgc    = (const float*)d_in[11];
    const float* gcbn_g = (const float*)d_in[12];
    const float* gcbn_b = (const float*)d_in[13];
    const float* bn_g   = (const float*)d_in[14];
    const float* bn_b   = (const float*)d_in[15];
    const float* obn_g  = (const float*)d_in[16];
    const float* obn_b  = (const float*)d_in[17];
    float* out = (float*)d_out;

    ushort_t* P0    = (ushort_t*)d_ws;
    ushort_t* P1    = P0 + BUF_;
    ushort_t* P2    = P1 + BUF_;
    ushort_t* P3    = P2 + BUF_;
    ushort_t* adjT  = P3 + BUF_;
    ushort_t* adj2T = adjT + 512 * 512;
    ushort_t* GT    = adj2T + 512 * 512;           // 5th big buffer (16 MiB)
    bool use_gt = ws_size >= 2ull * (5 * BUF_ + 2 * 512 * 512);

    k_transA<<<64, 256, 0, stream>>>(adj, adjT);
    k_sq<<<64, 256, 0, stream>>>(adjT, adj2T);
    k_start<<<4096, 256, 0, stream>>>(x, Wstart, bstart, P0);

    ushort_t* h  = P0;
    ushort_t* Gb = P1;
    for (int i = 0; i < 3; ++i) {
        int mode = (i == 0) ? 0 : ((i == 2) ? 2 : 1);
        k_gs_mfma<<<1024, 256, 0, stream>>>(h, Wf + i * 2048, bf_ + i * 32,
                                            Wg + i * 2048, bg + i * 32,
                                            Wskip + i * 1024, bskip + i * 32,
                                            Gb, out, L_ - i, 2 - i, mode, (i < 2) ? 1 : 0,
                                            obn_g, obn_b);
        if (i == 2) break;
        if (use_gt) {
            k_transG<<<2048, 256, 0, stream>>>(Gb, GT);
            k_diffuse2_gt<<<1024, 256, 0, stream>>>(GT, adjT, adj2T, P2, P3);
        } else {
            k_diffuse2_cnl<<<1024, 256, 0, stream>>>(Gb, adjT, adj2T, P2, P3);
        }
        k_gc3_mfma<<<1024, 256, 0, stream>>>(Gb, P2, P3, h,
                                             Wgc + i * 3072, bgc + i * 32,
                                             gcbn_g + i * 32, gcbn_b + i * 32,
                                             bn_g + i * 32, bn_b + i * 32);
        ushort_t* tmp = h; h = Gb; Gb = tmp;   // new h lives where G was
    }
}

// Round 10
// 334.251 us; speedup vs baseline: 1.0059x; 1.0059x over previous
//
#include <hip/hip_runtime.h>
#include <hip/hip_bf16.h>

#define B_     8
#define CIN_   2
#define N_     512
#define C_     32
#define L_     64
#define LOUT_  61
#define BUF_   ((size_t)(8*32*512*64))   // 8,388,608 bf16 elements per scratch buffer

typedef __hip_bfloat16 bf16;
typedef unsigned short ushort_t;
typedef __attribute__((ext_vector_type(8))) unsigned short us8;
typedef __attribute__((ext_vector_type(8))) short bf16x8;
typedef __attribute__((ext_vector_type(4))) float f32x4;

static __device__ __forceinline__ float bits2f(ushort_t u) {
    return __uint_as_float(((unsigned)u) << 16);
}
static __device__ __forceinline__ ushort_t f2bits(float v) {   // RNE bf16 (finite inputs)
    unsigned u = __float_as_uint(v);
    return (ushort_t)((u + 0x7fffu + ((u >> 16) & 1u)) >> 16);
}

// ---------------- K0: start 1x1 conv (2->32 ch). One octet of l per thread.
__global__ void k_start(const float* __restrict__ x,
                        const float* __restrict__ Wst,
                        const float* __restrict__ bst,
                        ushort_t* __restrict__ h) {
    int idx = blockIdx.x * 256 + threadIdx.x;      // octet id, 1,048,576 total
    int l0 = (idx & 7) * 8;
    int n  = (idx >> 3) & 511;
    int o  = (idx >> 12) & 31;
    int b  = idx >> 17;
    float w0 = Wst[o * 2], w1 = Wst[o * 2 + 1], bb = bst[o];
    int xbase = (b * CIN_ * N_ + n) * L_ + l0;
    float va[8], vb[8];
    *(float4*)&va[0] = *(const float4*)(x + xbase);
    *(float4*)&va[4] = *(const float4*)(x + xbase + 4);
    *(float4*)&vb[0] = *(const float4*)(x + xbase + N_ * L_);
    *(float4*)&vb[4] = *(const float4*)(x + xbase + N_ * L_ + 4);
    us8 r;
    #pragma unroll
    for (int k = 0; k < 8; ++k) r[k] = f2bits(bb + va[k] * w0 + vb[k] * w1);
    *(us8*)(h + (size_t)idx * 8) = r;
}

// ---------------- K_T: adjT[m][n] = bf16(adj[n][m]), one-shot 512x512 transpose
__global__ void k_transA(const float* __restrict__ adj, ushort_t* __restrict__ adjT) {
    __shared__ float buf[64][65];
    int ti = blockIdx.x & 7;        // n-tile
    int tj = blockIdx.x >> 3;       // m-tile
    int t = threadIdx.x;
    for (int r = 0; r < 16; ++r) {
        int e = t + 256 * r;
        int rl = e >> 6, cl = e & 63;
        buf[rl][cl] = adj[(size_t)(ti * 64 + rl) * 512 + tj * 64 + cl];
    }
    __syncthreads();
    for (int r = 0; r < 16; ++r) {
        int e = t + 256 * r;
        int ml = e >> 6, nl = e & 63;
        adjT[(size_t)(tj * 64 + ml) * 512 + ti * 64 + nl] = f2bits(buf[nl][ml]);
    }
}

// ---------------- K_SQ: adj2T = adjT x adjT  (= (A^2)^T), bf16 MFMA, one-shot
// per-row block rotation: phys_block = (logical_oct + row) & 7
__global__ __launch_bounds__(256, 2) void k_sq(const ushort_t* __restrict__ adjT,
                                               ushort_t* __restrict__ adj2T) {
    __shared__ __align__(16) ushort_t lds2[8192];   // As 4096 | Bs 4096; Ys aliases
    ushort_t* As = lds2;
    ushort_t* Bs = lds2 + 4096;
    int mt = blockIdx.x & 7, nc = blockIdx.x >> 3;
    int t = threadIdx.x, lane = t & 63, w = t >> 6;
    int la = lane & 15, q = lane >> 4;
    f32x4 acc[4];
    #pragma unroll
    for (int mi = 0; mi < 4; ++mi) acc[mi] = (f32x4)0.f;
    for (int p0 = 0; p0 < 512; p0 += 64) {
        __syncthreads();
        #pragma unroll
        for (int r = 0; r < 2; ++r) {
            int e = t + 256 * r, ml = e >> 3, oct = e & 7;
            int sw = ((oct + ml) & 7) << 3;
            *(us8*)(As + ml * 64 + sw) =
                *(const us8*)(adjT + (size_t)(mt * 64 + ml) * 512 + p0 + oct * 8);
            *(us8*)(Bs + ml * 64 + sw) =
                *(const us8*)(adjT + (size_t)(p0 + ml) * 512 + nc * 64 + oct * 8);
        }
        __syncthreads();
        #pragma unroll
        for (int ks = 0; ks < 2; ++ks) {
            bf16x8 a[4];
            #pragma unroll
            for (int mi = 0; mi < 4; ++mi) {
                int m = mi * 16 + la;
                int bl = (ks * 4 + q + m) & 7;
                a[mi] = *(const bf16x8*)(As + m * 64 + bl * 8);
            }
            bf16x8 bv;
            {
                int n = w * 16 + la;       // column n, gather across k rows
                int rot = (n + ks * 4 + q) & 7;
                int col = rot * 8 + (n & 7);
                // NOTE: Bs rows are k here (p-octets): scalar gather as before
                const ushort_t* p = Bs + (ks * 32 + q * 8) * 64;
                bf16x8 v;
                #pragma unroll
                for (int j = 0; j < 8; ++j) {
                    int row = ks * 32 + q * 8 + j;
                    int bl2 = (q + ks * 4 + row) & 7;   // unused; keep simple gather:
                    (void)bl2;
                    int blk = ((n >> 3) + row) & 7;
                    v[j] = (short)Bs[row * 64 + blk * 8 + (n & 7)];
                }
                (void)p; (void)rot; (void)col;
                bv = v;
            }
            #pragma unroll
            for (int mi = 0; mi < 4; ++mi)
                acc[mi] = __builtin_amdgcn_mfma_f32_16x16x32_bf16(a[mi], bv, acc[mi], 0, 0, 0);
        }
    }
    __syncthreads();
    ushort_t* Ys = lds2;   // [64][72]
    #pragma unroll
    for (int mi = 0; mi < 4; ++mi)
        #pragma unroll
        for (int r = 0; r < 4; ++r)
            Ys[(mi * 16 + q * 4 + r) * 72 + w * 16 + la] = f2bits(acc[mi][r]);
    __syncthreads();
    #pragma unroll
    for (int r = 0; r < 2; ++r) {
        int e = t + 256 * r, ml = e >> 3, oct = e & 7;
        us8 v = *(const us8*)(Ys + ml * 72 + oct * 8);
        *(us8*)(adj2T + (size_t)(mt * 64 + ml) * 512 + nc * 64 + oct * 8) = v;
    }
}

// ---------------- K_TG: GT[b][c][l][n] = G[b][c][n][l], per-depth 64x64-tile transpose
__global__ void k_transG(const ushort_t* __restrict__ Gsrc, ushort_t* __restrict__ GT) {
    __shared__ __align__(16) ushort_t buf[64 * 72];   // [l][n]
    int b  = blockIdx.x >> 8;
    int c  = (blockIdx.x >> 3) & 31;
    int nt = blockIdx.x & 7;
    int t = threadIdx.x;
    size_t base = (size_t)(b * 32 + c) * 32768;
    int n0 = nt * 64;
    #pragma unroll
    for (int r = 0; r < 2; ++r) {        // n-fast lanes: conflict-free LDS writes
        int e = t + 256 * r;
        int n = e & 63, loct = e >> 6;
        us8 v = *(const us8*)(Gsrc + base + (size_t)(n0 + n) * 64 + loct * 8);
        #pragma unroll
        for (int k = 0; k < 8; ++k) buf[(loct * 8 + k) * 72 + n] = v[k];
    }
    __syncthreads();
    #pragma unroll
    for (int r = 0; r < 2; ++r) {
        int e = t + 256 * r;
        int oct = e & 7, l = (e >> 3) & 63;
        us8 v = *(const us8*)(buf + l * 72 + oct * 8);
        *(us8*)(GT + base + (size_t)l * 512 + n0 + oct * 8) = v;
    }
}

// ---------------- K1: FUSED MFMA gated conv + skip conv (+ optional output BN)
__global__ __launch_bounds__(256, 2) void k_gs_mfma(
        const ushort_t* __restrict__ h,
        const float* __restrict__ Wf, const float* __restrict__ bfp,
        const float* __restrict__ Wg, const float* __restrict__ bgp,
        const float* __restrict__ Wsk, const float* __restrict__ bsk,
        ushort_t* __restrict__ G, float* __restrict__ out,
        int Llen, int off, int mode, int storeG,
        const float* __restrict__ og, const float* __restrict__ obb) {
    __shared__ __align__(16) ushort_t Ht[4 * 66 * 40];  // [node][l 0..65][c]
    __shared__ __align__(16) ushort_t Hs[128 * 72];     // G-tile -> St(float[128][36])
    __shared__ __align__(16) ushort_t Asf[32 * 72];
    __shared__ __align__(16) ushort_t Asg[32 * 72];
    __shared__ __align__(16) ushort_t As2[32 * 40];
    __shared__ float bfv[32], bgv[32], bsv[32];
    int t = threadIdx.x;
    int b = blockIdx.x >> 7, n0 = (blockIdx.x & 127) * 4;
    int lane = t & 63, w = t >> 6;
    int la = lane & 15, q = lane >> 4;

    {
        int o = t >> 3, k8 = (t & 7) * 8;
        us8 vf, vg;
        #pragma unroll
        for (int i = 0; i < 8; ++i) {
            int k = k8 + i, c = k & 31, tap = k >> 5;
            vf[i] = f2bits(Wf[o * 64 + c * 2 + tap]);
            vg[i] = f2bits(Wg[o * 64 + c * 2 + tap]);
        }
        *(us8*)(Asf + o * 72 + k8) = vf;
        *(us8*)(Asg + o * 72 + k8) = vg;
        if (k8 < 32) {
            us8 vs;
            #pragma unroll
            for (int i = 0; i < 8; ++i) vs[i] = f2bits(Wsk[o * 32 + k8 + i]);
            *(us8*)(As2 + o * 40 + k8) = vs;
        }
        if (t < 32) { bfv[t] = bfp[t]; bgv[t] = bgp[t]; bsv[t] = bsk[t]; }
    }
    #pragma unroll
    for (int r = 0; r < 2; ++r) {
        int idx = t + 256 * r;
        int lz = Llen + (idx >> 7);
        int node = (idx >> 5) & 3, c = idx & 31;
        if (lz < 66) Ht[(node * 66 + lz) * 40 + c] = 0;
    }
    const ushort_t* hb = h + (size_t)(b * 32) * 512 * 64;
    #pragma unroll
    for (int r = 0; r < 4; ++r) {
        int e = t + 256 * r;
        int row = e & 127, loct = e >> 7;
        int c = row >> 2, node = row & 3;
        us8 v = *(const us8*)(hb + ((size_t)c * 512 + n0 + node) * 64 + loct * 8);
        #pragma unroll
        for (int k = 0; k < 8; ++k) {
            int l = loct * 8 + k;
            if (l < Llen) Ht[(node * 66 + l) * 40 + c] = v[k];
        }
    }
    __syncthreads();

    bf16x8 af[2][2], ag[2][2];
    #pragma unroll
    for (int mt = 0; mt < 2; ++mt)
        #pragma unroll
        for (int ks = 0; ks < 2; ++ks) {
            af[mt][ks] = *(const bf16x8*)(Asf + (mt * 16 + la) * 72 + ks * 32 + q * 8);
            ag[mt][ks] = *(const bf16x8*)(Asg + (mt * 16 + la) * 72 + ks * 32 + q * 8);
        }

    f32x4 fa[2][4], ga[2][4];
    #pragma unroll
    for (int mt = 0; mt < 2; ++mt)
        #pragma unroll
        for (int ct = 0; ct < 4; ++ct) { fa[mt][ct] = (f32x4)0.f; ga[mt][ct] = (f32x4)0.f; }
    #pragma unroll
    for (int ct = 0; ct < 4; ++ct) {
        int lcol = ct * 16 + la;
        #pragma unroll
        for (int ks = 0; ks < 2; ++ks) {
            bf16x8 bv = *(const bf16x8*)(Ht + (w * 66 + lcol + ks) * 40 + q * 8);
            #pragma unroll
            for (int mt = 0; mt < 2; ++mt) {
                fa[mt][ct] = __builtin_amdgcn_mfma_f32_16x16x32_bf16(af[mt][ks], bv, fa[mt][ct], 0, 0, 0);
                ga[mt][ct] = __builtin_amdgcn_mfma_f32_16x16x32_bf16(ag[mt][ks], bv, ga[mt][ct], 0, 0, 0);
            }
        }
    }

    #pragma unroll
    for (int mt = 0; mt < 2; ++mt)
        #pragma unroll
        for (int ct = 0; ct < 4; ++ct)
            #pragma unroll
            for (int r = 0; r < 4; ++r) {
                int o = mt * 16 + q * 4 + r;
                float fv = fa[mt][ct][r] + bfv[o];
                float gv = ga[mt][ct][r] + bgv[o];
                float ef = __expf(2.f * fv);
                float act = (1.f - 2.f / (ef + 1.f)) * (1.f / (1.f + __expf(-gv)));
                int l = ct * 16 + la;
                int row = o * 4 + w;
                int sw = ((l >> 3) + row + (row >> 5)) & 7;
                Hs[row * 72 + sw * 8 + (l & 7)] = f2bits(act);
            }

    bf16x8 a2[2];
    a2[0] = *(const bf16x8*)(As2 + la * 40 + q * 8);
    a2[1] = *(const bf16x8*)(As2 + (16 + la) * 40 + q * 8);
    f32x4 sa[2][4];
    #pragma unroll
    for (int mt = 0; mt < 2; ++mt)
        #pragma unroll
        for (int ct = 0; ct < 4; ++ct) sa[mt][ct] = (f32x4)0.f;
    #pragma unroll
    for (int ct = 0; ct < 4; ++ct) {
        int le = ct * 16 + la + off;
        bf16x8 bv;
        #pragma unroll
        for (int j = 0; j < 8; ++j) {
            int row = 32 * q + 4 * j + w;
            int pos = (le < 64) ? ((((le >> 3) + row + q) & 7) * 8 + (le & 7)) : le;
            bv[j] = (short)Hs[row * 72 + pos];
        }
        sa[0][ct] = __builtin_amdgcn_mfma_f32_16x16x32_bf16(a2[0], bv, sa[0][ct], 0, 0, 0);
        sa[1][ct] = __builtin_amdgcn_mfma_f32_16x16x32_bf16(a2[1], bv, sa[1][ct], 0, 0, 0);
    }
    __syncthreads();

    if (storeG) {
        #pragma unroll
        for (int r = 0; r < 4; ++r) {
            int e = t + 256 * r;
            int row = e >> 3, oct = e & 7;
            int sw = (oct + row + (row >> 5)) & 7;
            us8 v = *(const us8*)(Hs + row * 72 + sw * 8);
            *(us8*)(G + ((size_t)(b * 32 + (row >> 2)) * 512 + n0 + (row & 3)) * 64 + oct * 8) = v;
        }
    }
    __syncthreads();

    float* St = (float*)Hs;
    const float rbn = rsqrtf(1.f + 1e-5f);
    #pragma unroll
    for (int half = 0; half < 2; ++half) {
        if ((w >> 1) == half) {
            #pragma unroll
            for (int mt = 0; mt < 2; ++mt)
                #pragma unroll
                for (int ct = 0; ct < 4; ++ct) {
                    int col = (w & 1) * 64 + ct * 16 + la;
                    int ob = mt * 16 + q * 4;
                    float4 sv = make_float4(sa[mt][ct][0] + bsv[ob],
                                            sa[mt][ct][1] + bsv[ob + 1],
                                            sa[mt][ct][2] + bsv[ob + 2],
                                            sa[mt][ct][3] + bsv[ob + 3]);
                    *(float4*)(St + col * 36 + ob) = sv;
                }
        }
        __syncthreads();
        {
            int col = t >> 1, o0 = (t & 1) * 16;
            int nr = half * 2 + (col >> 6), l = col & 63;
            if (l < LOUT_) {
                float* po = out + ((size_t)(b * LOUT_ + l) * 512 + n0 + nr) * 32 + o0;
                #pragma unroll
                for (int i = 0; i < 4; ++i) {
                    float4 s = *(float4*)(St + col * 36 + o0 + i * 4);
                    if (mode == 0) {
                        *(float4*)(po + i * 4) = s;
                    } else {
                        float4 old = *(float4*)(po + i * 4);
                        float4 vv = make_float4(old.x + s.x, old.y + s.y,
                                                old.z + s.z, old.w + s.w);
                        if (mode == 2) {
                            int ob = o0 + i * 4;
                            vv.x = vv.x * (og[ob] * rbn) + obb[ob];
                            vv.y = vv.y * (og[ob + 1] * rbn) + obb[ob + 1];
                            vv.z = vv.z * (og[ob + 2] * rbn) + obb[ob + 2];
                            vv.w = vv.w * (og[ob + 3] * rbn) + obb[ob + 3];
                        }
                        *(float4*)(po + i * 4) = vv;
                    }
                }
            }
        }
        __syncthreads();
    }
}

// ---------------- K3a: dual MFMA diffusion from GT — per-row swizzle, all-b128
__global__ __launch_bounds__(256, 3) void k_diffuse2_gt(
        const ushort_t* __restrict__ GT, const ushort_t* __restrict__ adjT,
        const ushort_t* __restrict__ adj2T,
        ushort_t* __restrict__ Y1, ushort_t* __restrict__ Y2) {
    __shared__ __align__(16) ushort_t lds[16384];  // As1|As2|Xs_t; Ys aliases
    ushort_t* As1 = lds;
    ushort_t* As2 = lds + 4096;
    ushort_t* Xs  = lds + 8192;                    // [2 c][64 l][64 n] swizzled
    int cp = blockIdx.x & 15;
    int mt = (blockIdx.x >> 4) & 7;
    int b  = blockIdx.x >> 7;
    int t  = threadIdx.x;
    int lane = t & 63, w = t >> 6;
    int c_loc = w & 1, lh = w >> 1;
    int m0 = mt * 64;
    int la = lane & 15, q = lane >> 4;
    const ushort_t* GTb = GT + (size_t)(b * 32 + cp * 2) * 32768;
    f32x4 acc1[4][2], acc2[4][2];
    #pragma unroll
    for (int mi = 0; mi < 4; ++mi)
        #pragma unroll
        for (int li = 0; li < 2; ++li) { acc1[mi][li] = (f32x4)0.f; acc2[mi][li] = (f32x4)0.f; }

    for (int n0 = 0; n0 < 512; n0 += 64) {
        __syncthreads();
        #pragma unroll
        for (int r = 0; r < 2; ++r) {
            int e = t + 256 * r;
            int ml = e >> 3, oct = e & 7;
            int sw = ((oct + ml) & 7) << 3;        // per-row rotation
            *(us8*)(As1 + ml * 64 + sw) =
                *(const us8*)(adjT + (size_t)(m0 + ml) * 512 + n0 + oct * 8);
            *(us8*)(As2 + ml * 64 + sw) =
                *(const us8*)(adj2T + (size_t)(m0 + ml) * 512 + n0 + oct * 8);
        }
        #pragma unroll
        for (int r = 0; r < 4; ++r) {              // stage Xs_t rows (c,l), n-contig
            int e = t + 256 * r;
            int row = e >> 3, oct = e & 7;         // row = cl*64 + l
            int cl = row >> 6, l = row & 63;
            us8 v = *(const us8*)(GTb + (size_t)cl * 32768 + (size_t)l * 512 + n0 + oct * 8);
            *(us8*)(Xs + cl * 4096 + l * 64 + (((oct + l) & 7) << 3)) = v;
        }
        __syncthreads();
        #pragma unroll
        for (int ks = 0; ks < 2; ++ks) {
            bf16x8 a1[4], a2v[4];
            #pragma unroll
            for (int mi = 0; mi < 4; ++mi) {
                int m = mi * 16 + la;
                int bl = (ks * 4 + q + m) & 7;     // per-row rotation
                a1[mi]  = *(const bf16x8*)(As1 + m * 64 + bl * 8);
                a2v[mi] = *(const bf16x8*)(As2 + m * 64 + bl * 8);
            }
            bf16x8 bb[2];
            #pragma unroll
            for (int li = 0; li < 2; ++li) {       // b128: row l, n-contig
                int l = lh * 32 + li * 16 + la;
                int bl = (ks * 4 + q + l) & 7;     // per-row rotation
                bb[li] = *(const bf16x8*)(Xs + c_loc * 4096 + l * 64 + bl * 8);
            }
            #pragma unroll
            for (int mi = 0; mi < 4; ++mi)
                #pragma unroll
                for (int li = 0; li < 2; ++li) {
                    acc1[mi][li] = __builtin_amdgcn_mfma_f32_16x16x32_bf16(a1[mi], bb[li], acc1[mi][li], 0, 0, 0);
                    acc2[mi][li] = __builtin_amdgcn_mfma_f32_16x16x32_bf16(a2v[mi], bb[li], acc2[mi][li], 0, 0, 0);
                }
        }
    }
    ushort_t* Ys = lds;                            // [2][64][72]
    #pragma unroll
    for (int pass = 0; pass < 2; ++pass) {
        __syncthreads();
        f32x4 (*src)[2] = pass ? acc2 : acc1;
        #pragma unroll
        for (int mi = 0; mi < 4; ++mi)
            #pragma unroll
            for (int li = 0; li < 2; ++li)
                #pragma unroll
                for (int r = 0; r < 4; ++r) {
                    int row = mi * 16 + q * 4 + r;
                    int col = lh * 32 + li * 16 + la;
                    Ys[c_loc * 4608 + row * 72 + col] = f2bits(src[mi][li][r]);
                }
        __syncthreads();
        ushort_t* Yo = pass ? Y2 : Y1;
        int c = t >> 7, mrem = t & 127;
        int m = mrem >> 1, lq = mrem & 1;
        #pragma unroll
        for (int r = 0; r < 4; ++r) {
            int l0 = lq * 32 + r * 8;
            us8 v = *(const us8*)(Ys + c * 4608 + m * 72 + l0);
            *(us8*)(Yo + ((size_t)(b * 32 + cp * 2 + c) * 512 + m0 + m) * 64 + l0) = v;
        }
    }
}

// ---------------- K4: MFMA graph-conv(96->32) + gcBN + residual + BN, in place over G.
__global__ __launch_bounds__(256, 2) void k_gc3_mfma(
        ushort_t* __restrict__ G, const ushort_t* __restrict__ X1,
        const ushort_t* __restrict__ X2, const ushort_t* __restrict__ hres,
        const float* __restrict__ Wgc, const float* __restrict__ bgc,
        const float* __restrict__ gg, const float* __restrict__ gb,
        const float* __restrict__ bg2, const float* __restrict__ bb2) {
    __shared__ __align__(16) ushort_t cat[384 * 72];   // B rows k*4+nr; reused as out tile
    __shared__ __align__(16) ushort_t hr[128 * 64];
    __shared__ __align__(16) ushort_t Aw[32 * 104];
    __shared__ float prm[5][32];
    int t = threadIdx.x;
    int b = blockIdx.x >> 7, n0 = (blockIdx.x & 127) * 4;
    int lane = t & 63, w = t >> 6;
    int la = lane & 15, q = lane >> 4;

    #pragma unroll
    for (int r = 0; r < 12; ++r) {
        int e = t + 256 * r;
        int row = e >> 3, oct = e & 7;
        int k = row >> 2;
        const ushort_t* src = (k < 32) ? G : ((k < 64) ? X1 : X2);
        us8 v = *(const us8*)(src + ((size_t)(b * 32 + (k & 31)) * 512 + n0 + (row & 3)) * 64 + oct * 8);
        int sw = (oct + row + (row >> 5)) & 7;
        *(us8*)(cat + row * 72 + sw * 8) = v;
    }
    #pragma unroll
    for (int r = 0; r < 4; ++r) {
        int e = t + 256 * r;
        int row = e >> 3, oct = e & 7;
        us8 v = *(const us8*)(hres + ((size_t)(b * 32 + (row >> 2)) * 512 + n0 + (row & 3)) * 64 + oct * 8);
        *(us8*)(hr + row * 64 + oct * 8) = v;
    }
    for (int e = t; e < 384; e += 256) {
        int o = e / 12, oct = e % 12;
        us8 v;
        #pragma unroll
        for (int i = 0; i < 8; ++i) v[i] = f2bits(Wgc[o * 96 + oct * 8 + i]);
        *(us8*)(Aw + o * 104 + oct * 8) = v;
    }
    if (t < 32) {
        prm[0][t] = bgc[t]; prm[1][t] = gg[t]; prm[2][t] = gb[t];
        prm[3][t] = bg2[t]; prm[4][t] = bb2[t];
    }
    __syncthreads();

    bf16x8 a[2][3];
    #pragma unroll
    for (int mt = 0; mt < 2; ++mt)
        #pragma unroll
        for (int ks = 0; ks < 3; ++ks)
            a[mt][ks] = *(const bf16x8*)(Aw + (mt * 16 + la) * 104 + ks * 32 + q * 8);

    f32x4 acc[2][4];
    #pragma unroll
    for (int mt = 0; mt < 2; ++mt)
        #pragma unroll
        for (int ct = 0; ct < 4; ++ct) acc[mt][ct] = (f32x4)0.f;
    #pragma unroll
    for (int ct = 0; ct < 4; ++ct) {
        int le = ct * 16 + la;
        #pragma unroll
        for (int ks = 0; ks < 3; ++ks) {
            bf16x8 bv;
            #pragma unroll
            for (int j = 0; j < 8; ++j) {
                int row = (ks * 32 + q * 8 + j) * 4 + w;
                int sw = ((le >> 3) + row + (row >> 5)) & 7;
                bv[j] = (short)cat[row * 72 + sw * 8 + (le & 7)];
            }
            acc[0][ct] = __builtin_amdgcn_mfma_f32_16x16x32_bf16(a[0][ks], bv, acc[0][ct], 0, 0, 0);
            acc[1][ct] = __builtin_amdgcn_mfma_f32_16x16x32_bf16(a[1][ks], bv, acc[1][ct], 0, 0, 0);
        }
    }
    __syncthreads();

    const float rbn = rsqrtf(1.f + 1e-5f);
    #pragma unroll
    for (int mt = 0; mt < 2; ++mt)
        #pragma unroll
        for (int ct = 0; ct < 4; ++ct)
            #pragma unroll
            for (int r = 0; r < 4; ++r) {
                int o = mt * 16 + q * 4 + r;
                int l = ct * 16 + la;
                float v = acc[mt][ct][r] + prm[0][o];
                v = v * (prm[1][o] * rbn) + prm[2][o];
                float res = (l < 63) ? bits2f(hr[(o * 4 + w) * 64 + l + 1]) : 0.f;
                v = (v + res) * (prm[3][o] * rbn) + prm[4][o];
                int row = o * 4 + w;
                int sw = ((l >> 3) + row + (row >> 5)) & 7;
                cat[row * 72 + sw * 8 + (l & 7)] = f2bits(v);
            }
    __syncthreads();
    #pragma unroll
    for (int r = 0; r < 4; ++r) {
        int e = t + 256 * r;
        int row = e >> 3, oct = e & 7;
        int sw = (oct + row + (row >> 5)) & 7;
        us8 v = *(const us8*)(cat + row * 72 + sw * 8);
        *(us8*)(G + ((size_t)(b * 32 + (row >> 2)) * 512 + n0 + (row & 3)) * 64 + oct * 8) = v;
    }
}

extern "C" void kernel_launch(void* const* d_in, const int* in_sizes, int n_in,
                              void* d_out, int out_size, void* d_ws, size_t ws_size,
                              hipStream_t stream) {
    const float* x      = (const float*)d_in[0];
    const float* adj    = (const float*)d_in[1];
    const float* Wstart = (const float*)d_in[2];
    const float* bstart = (const float*)d_in[3];
    const float* Wf     = (const float*)d_in[4];
    const float* bf_    = (const float*)d_in[5];
    const float* Wg     = (const float*)d_in[6];
    const float* bg     = (const float*)d_in[7];
    const float* Wskip  = (const float*)d_in[8];
    const float* bskip  = (const float*)d_in[9];
    const float* Wgc    = (const float*)d_in[10];
    const float* bgc    = (const float*)d_in[11];
    const float* gcbn_g = (const float*)d_in[12];
    const float* gcbn_b = (const float*)d_in[13];
    const float* bn_g   = (const float*)d_in[14];
    const float* bn_b   = (const float*)d_in[15];
    const float* obn_g  = (const float*)d_in[16];
    const float* obn_b  = (const float*)d_in[17];
    float* out = (float*)d_out;

    ushort_t* P0    = (ushort_t*)d_ws;
    ushort_t* P1    = P0 + BUF_;
    ushort_t* P2    = P1 + BUF_;
    ushort_t* P3    = P2 + BUF_;
    ushort_t* adjT  = P3 + BUF_;
    ushort_t* adj2T = adjT + 512 * 512;
    ushort_t* GT    = adj2T + 512 * 512;           // 5th big buffer (16 MiB; ws=256 MiB)

    k_transA<<<64, 256, 0, stream>>>(adj, adjT);
    k_sq<<<64, 256, 0, stream>>>(adjT, adj2T);
    k_start<<<4096, 256, 0, stream>>>(x, Wstart, bstart, P0);

    ushort_t* h  = P0;
    ushort_t* Gb = P1;
    for (int i = 0; i < 3; ++i) {
        int mode = (i == 0) ? 0 : ((i == 2) ? 2 : 1);
        k_gs_mfma<<<1024, 256, 0, stream>>>(h, Wf + i * 2048, bf_ + i * 32,
                                            Wg + i * 2048, bg + i * 32,
                                            Wskip + i * 1024, bskip + i * 32,
                                            Gb, out, L_ - i, 2 - i, mode, (i < 2) ? 1 : 0,
                                            obn_g, obn_b);
        if (i == 2) break;
        k_transG<<<2048, 256, 0, stream>>>(Gb, GT);
        k_diffuse2_gt<<<1024, 256, 0, stream>>>(GT, adjT, adj2T, P2, P3);
        k_gc3_mfma<<<1024, 256, 0, stream>>>(Gb, P2, P3, h,
                                             Wgc + i * 3072, bgc + i * 32,
                                             gcbn_g + i * 32, gcbn_b + i * 32,
                                             bn_g + i * 32, bn_b + i * 32);
        ushort_t* tmp = h; h = Gb; Gb = tmp;   // new h lives where G was
    }
}